// Round 1
// baseline (540.762 us; speedup 1.0000x reference)
//
#include <hip/hip_runtime.h>

#define HH 540
#define WW 960
#define NB 16
#define NPB (HH * WW)                 // 518400 rows per batch
#define NF  (NPB * 5)                 // 2,592,000 floats of rect per batch
static const float STRIDE_F = (float)(1919.0 / 959.0);
#define THR 0.6f

// ---------------- kernel 1: zero column counters ----------------
__global__ void k_zero(int* __restrict__ p, int n) {
    int i = blockIdx.x * blockDim.x + threadIdx.x;
    if (i < n) p[i] = 0;
}

// ---------------- kernel 2: per-column mask counts ----------------
// column w of batch b: count of cls[b,h,w,1] >= THR over h
__global__ void k_count(const float* __restrict__ cls, int* __restrict__ colcnt) {
    int w = blockIdx.x * 256 + threadIdx.x;
    int b = blockIdx.z;
    int h0 = blockIdx.y * 54;           // 540 = 10 * 54
    if (w >= WW) return;
    const float* base = cls + (size_t)b * NPB * 2;
    int c = 0;
    for (int h = h0; h < h0 + 54; ++h)
        c += (base[(size_t)(h * WW + w) * 2 + 1] >= THR) ? 1 : 0;
    if (c) atomicAdd(&colcnt[b * WW + w], c);
}

// ---------------- kernel 3: per-batch scan of column counts ----------------
__global__ void k_scan(const int* __restrict__ colcnt, int* __restrict__ colbase,
                       int* __restrict__ totals, const float* __restrict__ img,
                       float* __restrict__ out_img) {
    __shared__ int s[1024];
    int b = blockIdx.x;
    int t = threadIdx.x;
    int v = (t < WW) ? colcnt[b * WW + t] : 0;
    s[t] = v;
    __syncthreads();
    for (int d = 1; d < 1024; d <<= 1) {
        int x = s[t];
        int y = (t >= d) ? s[t - d] : 0;
        __syncthreads();
        s[t] = x + y;
        __syncthreads();
    }
    if (t < WW) colbase[b * WW + t] = s[t] - v;   // exclusive prefix
    if (t == 0) totals[b] = s[1023];
    if (t < 2) out_img[b * 2 + t] = img[b * 2 + t] + 1.0f;
}

// ---------------- kernel 4: compact (stable, column-major n-order) ----------------
__global__ __launch_bounds__(256) void k_compact(const float* __restrict__ cls,
                                                 const float4* __restrict__ roi,
                                                 const int* __restrict__ colbase,
                                                 float* __restrict__ out1,
                                                 float* __restrict__ out2) {
    __shared__ int msk[16][16];
    int t = threadIdx.x;
    int w_l = t & 15;
    int h_l = t >> 4;
    int b = blockIdx.y;
    int w = blockIdx.x * 16 + w_l;
    const float*  cbase = cls + (size_t)b * NPB * 2;
    const float4* rbase = roi + (size_t)b * NPB;
    int cb  = colbase[b * WW + w];
    int run = 0;
    float sxw = truncf(STRIDE_F * (float)w);
    float exw = truncf(STRIDE_F * (float)w + 11.0f);
    for (int ih = 0; ih < 34; ++ih) {       // 34*16 = 544 >= 540
        int h = ih * 16 + h_l;
        bool valid = h < HH;
        float p = 0.0f;
        float4 r = make_float4(0.f, 0.f, 0.f, 0.f);
        if (valid) {
            p = cbase[(size_t)(h * WW + w) * 2 + 1];
            r = rbase[h * WW + w];
        }
        int m = (valid && p >= THR) ? 1 : 0;
        __syncthreads();                    // protect msk reuse
        msk[h_l][w_l] = m;
        __syncthreads();
        int off = 0, tot = 0;
#pragma unroll
        for (int i = 0; i < 16; ++i) {
            int v = msk[i][w_l];
            tot += v;
            if (i < h_l) off += v;
        }
        if (m) {
            float sy = truncf(STRIDE_F * (float)h);
            float ey = truncf(STRIDE_F * (float)h + 11.0f);
            float x1 = sxw + r.x * 12.0f;
            float y1 = sy  + r.y * 12.0f;
            float x2 = exw + r.z * 12.0f;
            float y2 = ey  + r.w * 12.0f;
            float wd = x2 - x1;
            float hd = y2 - y1;
            float l  = fmaxf(wd, hd);
            float nx1 = x1 + wd * 0.5f - l * 0.5f;
            float ny1 = y1 + hd * 0.5f - l * 0.5f;
            int pos = cb + run + off;
            size_t o = ((size_t)b * NPB + (size_t)pos) * 5;
            out1[o + 0] = nx1; out1[o + 1] = ny1; out1[o + 2] = nx1 + l;
            out1[o + 3] = ny1 + l; out1[o + 4] = p;
            out2[o + 0] = nx1; out2[o + 1] = ny1; out2[o + 2] = nx1 + l;
            out2[o + 3] = ny1 + l; out2[o + 4] = p;
        }
        run += tot;
    }
}

// ---------------- kernel 5: zero the tail rows [K, NPB) ----------------
__global__ void k_ztail(const int* __restrict__ totals, float* __restrict__ out1,
                        float* __restrict__ out2) {
    int b = blockIdx.y;
    int K5 = totals[b] * 5;
    int chunk = blockIdx.x * blockDim.x + threadIdx.x;   // float4 chunk idx in batch
    int f0 = chunk * 4;
    if (f0 >= NF) return;
    size_t base = (size_t)b * NF;
    if (f0 >= K5) {
        float4 z = make_float4(0.f, 0.f, 0.f, 0.f);
        *(float4*)(out1 + base + f0) = z;
        *(float4*)(out2 + base + f0) = z;
    } else if (f0 + 4 > K5) {
        for (int j = K5; j < f0 + 4; ++j) {
            out1[base + j] = 0.0f;
            out2[base + j] = 0.0f;
        }
    }
}

extern "C" void kernel_launch(void* const* d_in, const int* in_sizes, int n_in,
                              void* d_out, int out_size, void* d_ws, size_t ws_size,
                              hipStream_t stream) {
    const float* cls = (const float*)d_in[0];   // [16,540,960,2]
    const float* roi = (const float*)d_in[1];   // [16,540,960,4]
    const float* img = (const float*)d_in[2];   // [16,2]

    float* out1 = (float*)d_out;                     // rect copy 1
    float* out2 = out1 + (size_t)NB * NF;            // rect copy 2
    float* outimg = out2 + (size_t)NB * NF;          // img + 1

    int* colcnt  = (int*)d_ws;                       // [16*960]
    int* colbase = colcnt + NB * WW;                 // [16*960]
    int* totals  = colbase + NB * WW;                // [16]

    k_zero<<<dim3((NB * WW + 255) / 256), dim3(256), 0, stream>>>(colcnt, NB * WW);
    k_count<<<dim3(4, 10, NB), dim3(256), 0, stream>>>(cls, colcnt);
    k_scan<<<dim3(NB), dim3(1024), 0, stream>>>(colcnt, colbase, totals, img, outimg);
    k_compact<<<dim3(60, NB), dim3(256), 0, stream>>>(cls, (const float4*)roi, colbase,
                                                      out1, out2);
    k_ztail<<<dim3((NF / 4 + 255) / 256, NB), dim3(256), 0, stream>>>(totals, out1, out2);
}

// Round 4
// 517.045 us; speedup vs baseline: 1.0459x; 1.0459x over previous
//
#include <hip/hip_runtime.h>

#define HH 540
#define WW 960
#define NB 16
#define NPB (HH * WW)                 // 518400 rows per batch
#define NF  (NPB * 5)                 // 2,592,000 floats of rect per batch
static const float STRIDE_F = (float)(1919.0 / 959.0);
#define THR 0.6f

// ---------------- kernel 0: zero column counters (graph-capture safe) ------------
__global__ void k_zero(int* __restrict__ p, int n) {
    int i = blockIdx.x * blockDim.x + threadIdx.x;
    if (i < n) p[i] = 0;
}

// ---------------- kernel 1: per-column mask counts (float4 reads) ----------------
// thread owns a pair of columns (w0, w0+1); reads cls as float4 = 2 pixels.
// cls has NPB*2 floats per batch = NPB/2 float4s per batch.
__global__ void k_count(const float4* __restrict__ cls4, int* __restrict__ colcnt) {
    int tw = blockIdx.x * 256 + threadIdx.x;     // w-pair index, [0, 480)
    int b = blockIdx.z;
    int h0 = blockIdx.y * 54;                    // 540 = 10 * 54
    if (tw >= WW / 2) return;
    int w0 = tw * 2;
    const float4* base = cls4 + (size_t)b * (NPB / 2);   // NPB/2 float4 per batch
    int c0 = 0, c1 = 0;
    for (int h = h0; h < h0 + 54; ++h) {
        float4 v = base[(size_t)(h * WW + w0) >> 1];
        c0 += (v.y >= THR) ? 1 : 0;
        c1 += (v.w >= THR) ? 1 : 0;
    }
    if (c0) atomicAdd(&colcnt[b * WW + w0], c0);
    if (c1) atomicAdd(&colcnt[b * WW + w0 + 1], c1);
}

// ---------------- kernel 2: per-batch scan of column counts ----------------
__global__ void k_scan(const int* __restrict__ colcnt, int* __restrict__ colbase,
                       int* __restrict__ totals, const float* __restrict__ img,
                       float* __restrict__ out_img) {
    __shared__ int s[1024];
    int b = blockIdx.x;
    int t = threadIdx.x;
    int v = (t < WW) ? colcnt[b * WW + t] : 0;
    s[t] = v;
    __syncthreads();
    for (int d = 1; d < 1024; d <<= 1) {
        int x = s[t];
        int y = (t >= d) ? s[t - d] : 0;
        __syncthreads();
        s[t] = x + y;
        __syncthreads();
    }
    if (t < WW) colbase[b * WW + t] = s[t] - v;   // exclusive prefix
    if (t == 0) totals[b] = s[1023];
    if (t < 2) out_img[b * 2 + t] = img[b * 2 + t] + 1.0f;
}

// ---------------- kernel 3: compact (stable) with LDS staging + coalesced flush ----
__global__ __launch_bounds__(256) void k_compact(const float* __restrict__ cls,
                                                 const float4* __restrict__ roi,
                                                 const int* __restrict__ colbase,
                                                 float* __restrict__ out1,
                                                 float* __restrict__ out2) {
    __shared__ int wcnt_s[4][16];            // per-wave per-column accepted counts
    __shared__ float rows_s[16 * 80];        // 16 columns x 16 rows x 5 floats (AoS)
    int t = threadIdx.x;
    int w_l = t & 15;                        // compute column within block
    int h_l = t >> 4;                        // compute row within chunk
    int wave = t >> 6;                       // wave id (0..3)
    int h_lw = h_l & 3;                      // row within wave (0..3)
    int b = blockIdx.y;
    int w = blockIdx.x * 16 + w_l;
    const float*  cbase = cls + (size_t)b * NPB * 2;
    const float4* rbase = roi + (size_t)b * NPB;

    // flush role: column fc = t/16, dword lane fj = t%16 (consecutive tid -> consecutive addr)
    int fc = h_l;
    int fj = w_l;
    int cb_f = colbase[b * WW + blockIdx.x * 16 + fc];
    int run_f = 0;

    float sxw = truncf(STRIDE_F * (float)w);
    float exw = truncf(STRIDE_F * (float)w + 11.0f);

    for (int ih = 0; ih < 34; ++ih) {        // 34*16 = 544 >= 540
        int h = ih * 16 + h_l;
        bool valid = h < HH;
        float p = valid ? cbase[(size_t)(h * WW + w) * 2 + 1] : 0.0f;
        bool m = valid && (p >= THR);

        unsigned long long bal = __ballot(m);
        unsigned long long colmask = 0x0001000100010001ULL << w_l;
        int off_w = __popcll(bal & colmask & ((1ULL << (h_lw * 16)) - 1ULL));
        int wc    = __popcll(bal & colmask);

        __syncthreads();                     // protect wcnt_s/rows_s from prev flush reads
        if (h_lw == 0) wcnt_s[wave][w_l] = wc;   // lanes 0..15 of each wave
        __syncthreads();

        int off = off_w;
#pragma unroll
        for (int v = 0; v < 4; ++v) {
            int x = wcnt_s[v][w_l];
            if (v < wave) off += x;
        }

        if (m) {
            float4 r = rbase[h * WW + w];
            float sy = truncf(STRIDE_F * (float)h);
            float ey = truncf(STRIDE_F * (float)h + 11.0f);
            float x1 = sxw + r.x * 12.0f;
            float y1 = sy  + r.y * 12.0f;
            float x2 = exw + r.z * 12.0f;
            float y2 = ey  + r.w * 12.0f;
            float wd = x2 - x1;
            float hd = y2 - y1;
            float l  = fmaxf(wd, hd);
            float nx1 = x1 + wd * 0.5f - l * 0.5f;
            float ny1 = y1 + hd * 0.5f - l * 0.5f;
            int sb = w_l * 80 + off * 5;     // stride-5 dwords: bank-conflict-free
            rows_s[sb + 0] = nx1;
            rows_s[sb + 1] = ny1;
            rows_s[sb + 2] = nx1 + l;
            rows_s[sb + 3] = ny1 + l;
            rows_s[sb + 4] = p;
        }
        __syncthreads();                     // rows_s complete before flush

        // flush: this thread copies dwords fj, fj+16, ... of column fc's chunk rows
        int tot_f = wcnt_s[0][fc] + wcnt_s[1][fc] + wcnt_s[2][fc] + wcnt_s[3][fc];
        int nd = tot_f * 5;
        size_t gb = ((size_t)b * NPB + (size_t)(cb_f + run_f)) * 5;
        for (int d = fj; d < nd; d += 16) {
            float val = rows_s[fc * 80 + d];
            out1[gb + d] = val;
            out2[gb + d] = val;
        }
        run_f += tot_f;
    }
}

// ---------------- kernel 4: zero the tail rows [K, NPB) ----------------
__global__ void k_ztail(const int* __restrict__ totals, float* __restrict__ out1,
                        float* __restrict__ out2) {
    int b = blockIdx.y;
    int K5 = totals[b] * 5;
    int chunk = blockIdx.x * blockDim.x + threadIdx.x;   // float4 chunk idx in batch
    int f0 = chunk * 4;
    if (f0 >= NF) return;
    size_t base = (size_t)b * NF;
    if (f0 >= K5) {
        float4 z = make_float4(0.f, 0.f, 0.f, 0.f);
        *(float4*)(out1 + base + f0) = z;
        *(float4*)(out2 + base + f0) = z;
    } else if (f0 + 4 > K5) {
        for (int j = K5; j < f0 + 4; ++j) {
            out1[base + j] = 0.0f;
            out2[base + j] = 0.0f;
        }
    }
}

extern "C" void kernel_launch(void* const* d_in, const int* in_sizes, int n_in,
                              void* d_out, int out_size, void* d_ws, size_t ws_size,
                              hipStream_t stream) {
    const float* cls = (const float*)d_in[0];   // [16,540,960,2]
    const float* roi = (const float*)d_in[1];   // [16,540,960,4]
    const float* img = (const float*)d_in[2];   // [16,2]

    float* out1 = (float*)d_out;                     // rect copy 1
    float* out2 = out1 + (size_t)NB * NF;            // rect copy 2
    float* outimg = out2 + (size_t)NB * NF;          // img + 1

    int* colcnt  = (int*)d_ws;                       // [16*960]
    int* colbase = colcnt + NB * WW;                 // [16*960]
    int* totals  = colbase + NB * WW;                // [16]

    k_zero<<<dim3((NB * WW + 255) / 256), dim3(256), 0, stream>>>(colcnt, NB * WW);
    k_count<<<dim3(2, 10, NB), dim3(256), 0, stream>>>((const float4*)cls, colcnt);
    k_scan<<<dim3(NB), dim3(1024), 0, stream>>>(colcnt, colbase, totals, img, outimg);
    k_compact<<<dim3(60, NB), dim3(256), 0, stream>>>(cls, (const float4*)roi, colbase,
                                                      out1, out2);
    k_ztail<<<dim3((NF / 4 + 255) / 256, NB), dim3(256), 0, stream>>>(totals, out1, out2);
}